// Round 3
// baseline (467.071 us; speedup 1.0000x reference)
//
#include <hip/hip_runtime.h>

#define NPTS      1048576
#define TABLE_SZ  1048577
#define NLEVELS   3
#define FDIM      8

// 16 lanes per point: lane = (point<<4) | (corner<<1) | half.
// Lane pair (2c, 2c+1) loads the two dwordx4 halves of one feature row in
// the SAME instruction -> TA merges them into one 64B line request,
// guaranteeing 24M (not 48M) L2 transactions for the gather stream.
__global__ __launch_bounds__(256) void octree_gather16(
    const float* __restrict__ coord,     // (NPTS, 3)
    const float* __restrict__ features,  // (NLEVELS, TABLE_SZ, 8)
    const int*   __restrict__ indices,   // (NLEVELS, NPTS, 8)
    float*       __restrict__ out)       // (NPTS, 8)
{
    const int tid = blockIdx.x * blockDim.x + threadIdx.x;
    const int h   = tid & 1;          // row half: floats [4h, 4h+4)
    const int c   = (tid >> 1) & 7;   // corner 0..7
    const int n   = tid >> 4;         // point index

    // coord (broadcast across the 16 lanes of a point)
    const float x = coord[3 * n + 0];
    const float y = coord[3 * n + 1];
    const float z = coord[3 * n + 2];

    // ---- index loads (coalesced, pairs of lanes broadcast-share a dword) ----
    int idx[NLEVELS];
    #pragma unroll
    for (int i = 0; i < NLEVELS; ++i)
        idx[i] = indices[(size_t)i * (size_t)NPTS * 8 + (size_t)n * 8 + c];

    // ---- issue all 3 gathers back-to-back (one dwordx4 per level) ----
    float4 g[NLEVELS];
    #pragma unroll
    for (int i = 0; i < NLEVELS; ++i) {
        const float* ft = features + (size_t)(NLEVELS - 1 - i) * (size_t)TABLE_SZ * FDIM;
        g[i] = *reinterpret_cast<const float4*>(ft + (size_t)idx[i] * FDIM + h * 4);
    }

    // ---- per-level smoothstep weights (overlap gather latency) ----
    float w[NLEVELS];
    #pragma unroll
    for (int i = 0; i < NLEVELS; ++i) {
        const float scale = (float)(2048 >> i);   // 2^(level-1), level = 12-i
        float cx = fmaf(scale, x, scale);
        float cy = fmaf(scale, y, scale);
        float cz = fmaf(scale, z, scale);
        float dx = cx - floorf(cx);
        float dy = cy - floorf(cy);
        float dz = cz - floorf(cz);
        dx = dx * dx * (3.0f - 2.0f * dx);
        dy = dy * dy * (3.0f - 2.0f * dy);
        dz = dz * dz * (3.0f - 2.0f * dz);
        float wi = ((c & 4) ? dx : 1.0f - dx)
                 * ((c & 2) ? dy : 1.0f - dy)
                 * ((c & 1) ? dz : 1.0f - dz);
        // reference zeroes features[:, -1, :]: mask the weight instead
        w[i] = (idx[i] == TABLE_SZ - 1) ? 0.0f : wi;
    }

    // ---- weighted accumulate (4 floats per lane) ----
    float4 acc = make_float4(0.f, 0.f, 0.f, 0.f);
    #pragma unroll
    for (int i = 0; i < NLEVELS; ++i) {
        acc.x = fmaf(w[i], g[i].x, acc.x);
        acc.y = fmaf(w[i], g[i].y, acc.y);
        acc.z = fmaf(w[i], g[i].z, acc.z);
        acc.w = fmaf(w[i], g[i].w, acc.w);
    }

    // ---- reduce over the 8 corners (lanes at stride 2, same h) ----
    #pragma unroll
    for (int m = 2; m <= 8; m <<= 1) {
        acc.x += __shfl_xor(acc.x, m);
        acc.y += __shfl_xor(acc.y, m);
        acc.z += __shfl_xor(acc.z, m);
        acc.w += __shfl_xor(acc.w, m);
    }

    // lanes with c==0 (two per point, h=0/1) hold the final halves.
    // Per wave: 4 points x 32B = 128B contiguous store region.
    if (c == 0) {
        *reinterpret_cast<float4*>(out + (size_t)n * FDIM + h * 4) = acc;
    }
}

extern "C" void kernel_launch(void* const* d_in, const int* in_sizes, int n_in,
                              void* d_out, int out_size, void* d_ws, size_t ws_size,
                              hipStream_t stream) {
    const float* coord    = (const float*)d_in[0];
    const float* features = (const float*)d_in[1];
    const int*   indices  = (const int*)d_in[2];
    float*       out      = (float*)d_out;

    const int block = 256;
    const long total_threads = (long)NPTS * 16;   // 16 lanes per point
    const int grid  = (int)((total_threads + block - 1) / block);  // 65536
    octree_gather16<<<grid, block, 0, stream>>>(coord, features, indices, out);
}